// Round 4
// baseline (361.824 us; speedup 1.0000x reference)
//
#include <hip/hip_runtime.h>

#define FD 128  // feature dim, fixed by problem

typedef __attribute__((ext_vector_type(8))) short short8;   // 8 bf16 in 4 VGPRs
typedef __attribute__((ext_vector_type(4))) float floatx4;  // MFMA acc

__device__ inline unsigned short f2bf(float f) {  // fp32 -> bf16 bits, RNE
  unsigned u = __float_as_uint(f);
  u += 0x7fffu + ((u >> 16) & 1u);
  return (unsigned short)(u >> 16);
}
__device__ inline float bf2f(unsigned short s) {
  return __uint_as_float(((unsigned)s) << 16);
}
__device__ inline float lo16f(unsigned v) { return __uint_as_float(v << 16); }
__device__ inline float hi16f(unsigned v) { return __uint_as_float(v & 0xffff0000u); }
__device__ inline int imin(int a, int b) { return a < b ? a : b; }

// ---------------- CSR construction ----------------

__global__ __launch_bounds__(256) void k_count(const int* __restrict__ dst,
                                               int* __restrict__ deg, int E) {
  int e = blockIdx.x * 256 + threadIdx.x;
  if (e < E) atomicAdd(&deg[dst[e]], 1);
}

// per-256-block exclusive scan + block totals + dis = rsqrt(deg+1)
__global__ __launch_bounds__(256) void k_scanA(const int* __restrict__ deg,
                                               int* __restrict__ offtmp,
                                               int* __restrict__ bsum,
                                               float* __restrict__ dis, int N) {
  __shared__ int s[256];
  int i = blockIdx.x * 256 + threadIdx.x;
  int v = (i < N) ? deg[i] : 0;
  if (i < N) dis[i] = rsqrtf((float)(v + 1));  // +1 self-loop
  s[threadIdx.x] = v;
  __syncthreads();
#pragma unroll
  for (int ofs = 1; ofs < 256; ofs <<= 1) {
    int t = (threadIdx.x >= ofs) ? s[threadIdx.x - ofs] : 0;
    __syncthreads();
    s[threadIdx.x] += t;
    __syncthreads();
  }
  if (i < N) offtmp[i] = s[threadIdx.x] - v;  // exclusive
  if (threadIdx.x == 255) bsum[blockIdx.x] = s[255];
}

// parallel exclusive scan of block sums (nb <= 512)
__global__ __launch_bounds__(512) void k_scanB(int* __restrict__ bsum, int nb) {
  __shared__ int s[512];
  int t = threadIdx.x;
  int v = (t < nb) ? bsum[t] : 0;
  s[t] = v;
  __syncthreads();
#pragma unroll
  for (int ofs = 1; ofs < 512; ofs <<= 1) {
    int u = (t >= ofs) ? s[t - ofs] : 0;
    __syncthreads();
    s[t] += u;
    __syncthreads();
  }
  if (t < nb) bsum[t] = s[t] - v;  // exclusive
}

__global__ __launch_bounds__(256) void k_scanC(const int* __restrict__ offtmp,
                                               const int* __restrict__ bsum,
                                               int* __restrict__ off, int N, int E) {
  int i = blockIdx.x * 256 + threadIdx.x;
  if (i < N) off[i] = offtmp[i] + bsum[i >> 8];
  if (i == 0) off[N] = E;
}

// packed edge record: .x = src, .y = bits(dis[src]*dis[dst])
__global__ __launch_bounds__(256) void k_fill(const int* __restrict__ src,
                                              const int* __restrict__ dst,
                                              const float* __restrict__ dis,
                                              const int* __restrict__ off,
                                              int* __restrict__ cursor,
                                              int2* __restrict__ ew, int E) {
  int e = blockIdx.x * 256 + threadIdx.x;
  if (e >= E) return;
  int d = dst[e], s = src[e];
  int pos = off[d] + atomicAdd(&cursor[d], 1);
  ew[pos] = make_int2(s, __float_as_int(dis[s] * dis[d]));
}

// ---------------- W pre-swizzle: fp32 W -> hi/lo bf16 in MFMA B-frag order ----
// Wf[ct][kt][lane][j]: k = kt*32 + (lane>>4)*8 + j, n = ct*16 + (lane&15)
__global__ __launch_bounds__(256) void k_wsplit(const float* __restrict__ W,
                                                short* __restrict__ hi,
                                                short* __restrict__ lo) {
  int idx = blockIdx.x * 256 + threadIdx.x;  // 0..16383
  int j = idx & 7, lane = (idx >> 3) & 63, kt = (idx >> 9) & 3, ct = idx >> 11;
  int k = kt * 32 + (lane >> 4) * 8 + j;
  int n = ct * 16 + (lane & 15);
  float w = W[k * FD + n];
  unsigned short h = f2bf(w);
  hi[idx] = (short)h;
  lo[idx] = (short)f2bf(w - bf2f(h));
}

// ---------------- GEMM: H(bf16) = A @ W via bf16 MFMA ----------------
// W hi (and optionally lo) fragments staged in LDS. 4 waves/block, 32 rows/wave.
// ABF16=false: A fp32, split hi/lo in-register. WLO: apply W low-order correction.
template <bool ABF16, bool WLO>
__global__ __launch_bounds__(256) void k_gemm(const void* __restrict__ Av,
                                              const short* __restrict__ Wf_hi,
                                              const short* __restrict__ Wf_lo,
                                              unsigned short* __restrict__ H, int N) {
  __shared__ short whi[FD * FD];            // 32 KB
  __shared__ short wlo[WLO ? FD * FD : 8];  // 32 KB when enabled
  int tid = threadIdx.x;
#pragma unroll
  for (int it = 0; it < 8; ++it) {
    int idx = (it * 256 + tid) * 8;  // 16 B per thread per iter
    *(short8*)&whi[idx] = *(const short8*)&Wf_hi[idx];
    if (WLO) *(short8*)&wlo[idx] = *(const short8*)&Wf_lo[idx];
  }
  __syncthreads();

  int wid = tid >> 6, lane = tid & 63;
  int quad = lane >> 4, m = lane & 15;
  int rbase = blockIdx.x * 128 + wid * 32;

  short8 ahi[2][4], alo[2][4];
#pragma unroll
  for (int t = 0; t < 2; ++t) {
    int arow = rbase + t * 16 + m;
    if (arow >= N) arow = N - 1;  // clamp; OOB rows never stored
    if (ABF16) {
      const unsigned short* ap = (const unsigned short*)Av + (size_t)arow * FD;
#pragma unroll
      for (int kt = 0; kt < 4; ++kt)
        ahi[t][kt] = *(const short8*)(ap + kt * 32 + quad * 8);
    } else {
      const float* ap = (const float*)Av + (size_t)arow * FD;
#pragma unroll
      for (int kt = 0; kt < 4; ++kt) {
        const float* p = ap + kt * 32 + quad * 8;
        float4 a0 = *(const float4*)p;
        float4 a1 = *(const float4*)(p + 4);
        float av[8] = {a0.x, a0.y, a0.z, a0.w, a1.x, a1.y, a1.z, a1.w};
#pragma unroll
        for (int j = 0; j < 8; ++j) {
          unsigned short hb = f2bf(av[j]);
          ahi[t][kt][j] = (short)hb;
          alo[t][kt][j] = (short)f2bf(av[j] - bf2f(hb));
        }
      }
    }
  }

#pragma unroll
  for (int ct = 0; ct < 8; ++ct) {
    floatx4 acc0 = {0.f, 0.f, 0.f, 0.f}, acc1 = {0.f, 0.f, 0.f, 0.f};
#pragma unroll
    for (int kt = 0; kt < 4; ++kt) {
      int fo = (((ct << 2) + kt) * 64 + lane) * 8;
      short8 bhi = *(const short8*)&whi[fo];
      acc0 = __builtin_amdgcn_mfma_f32_16x16x32_bf16(ahi[0][kt], bhi, acc0, 0, 0, 0);
      acc1 = __builtin_amdgcn_mfma_f32_16x16x32_bf16(ahi[1][kt], bhi, acc1, 0, 0, 0);
      if (!ABF16) {
        acc0 = __builtin_amdgcn_mfma_f32_16x16x32_bf16(alo[0][kt], bhi, acc0, 0, 0, 0);
        acc1 = __builtin_amdgcn_mfma_f32_16x16x32_bf16(alo[1][kt], bhi, acc1, 0, 0, 0);
      }
      if (WLO) {
        short8 blo = *(const short8*)&wlo[fo];
        acc0 = __builtin_amdgcn_mfma_f32_16x16x32_bf16(ahi[0][kt], blo, acc0, 0, 0, 0);
        acc1 = __builtin_amdgcn_mfma_f32_16x16x32_bf16(ahi[1][kt], blo, acc1, 0, 0, 0);
      }
    }
    // C/D: row = quad*4 + reg, col = lane&15
#pragma unroll
    for (int r = 0; r < 4; ++r) {
      int row0 = rbase + quad * 4 + r;
      int row1 = rbase + 16 + quad * 4 + r;
      if (row0 < N) H[(size_t)row0 * FD + ct * 16 + m] = f2bf(acc0[r]);
      if (row1 < N) H[(size_t)row1 * FD + ct * 16 + m] = f2bf(acc1[r]);
    }
  }
}

// ---------------- Aggregation: out = relu(A_norm @ h + b), h is bf16 --------
// One wave per 4 consecutive nodes = one contiguous CSR edge stream.
// 2-stage pipeline, 4-edge groups: 8 gathers in flight; ew/off via scalar loads.
template <bool OUTBF16>
__global__ __launch_bounds__(256) void k_agg(const unsigned int* __restrict__ h,
                                             const int* __restrict__ off,
                                             const int2* __restrict__ ew,
                                             const float* __restrict__ dis,
                                             const float* __restrict__ bias,
                                             void* __restrict__ out, int N) {
  int lane = threadIdx.x & 63;
  int i0 = __builtin_amdgcn_readfirstlane((blockIdx.x * 4 + (threadIdx.x >> 6)) * 4);
  if (i0 >= N) return;

  int b0 = off[i0];
  int b1 = off[imin(i0 + 1, N)];
  int b2 = off[imin(i0 + 2, N)];
  int b3 = off[imin(i0 + 3, N)];
  int b4 = off[imin(i0 + 4, N)];

  float ax[4], ay[4];
#pragma unroll
  for (int t = 0; t < 4; ++t) {
    int i = i0 + t;
    if (i < N) {
      float di = dis[i];
      float ws = di * di;
      unsigned v = h[(size_t)i * 64 + lane];
      ax[t] = ws * lo16f(v);
      ay[t] = ws * hi16f(v);
    } else {
      ax[t] = 0.f;
      ay[t] = 0.f;
    }
  }

  int p = b0, pe = b4;
  if (p < pe) {
    int2 e0[4], e1[4];
    unsigned g0[4];
#pragma unroll
    for (int j = 0; j < 4; ++j) e0[j] = ew[imin(p + j, pe - 1)];
#pragma unroll
    for (int j = 0; j < 4; ++j) g0[j] = h[(size_t)e0[j].x * 64 + lane];
#pragma unroll
    for (int j = 0; j < 4; ++j) e1[j] = ew[imin(p + 4 + j, pe - 1)];

    for (int q = p; q < pe; q += 4) {
      unsigned g1[4];
      int2 e2[4];
#pragma unroll
      for (int j = 0; j < 4; ++j) g1[j] = h[(size_t)e1[j].x * 64 + lane];  // next gathers
#pragma unroll
      for (int j = 0; j < 4; ++j) e2[j] = ew[imin(q + 8 + j, pe - 1)];     // ew 2 ahead
#pragma unroll
      for (int j = 0; j < 4; ++j) {
        int qq = q + j;
        if (qq < pe) {  // wave-uniform
          float w = __int_as_float(e0[j].y);
          float l = lo16f(g0[j]), hh = hi16f(g0[j]);
          if (qq < b1) {
            ax[0] = fmaf(w, l, ax[0]); ay[0] = fmaf(w, hh, ay[0]);
          } else if (qq < b2) {
            ax[1] = fmaf(w, l, ax[1]); ay[1] = fmaf(w, hh, ay[1]);
          } else if (qq < b3) {
            ax[2] = fmaf(w, l, ax[2]); ay[2] = fmaf(w, hh, ay[2]);
          } else {
            ax[3] = fmaf(w, l, ax[3]); ay[3] = fmaf(w, hh, ay[3]);
          }
        }
      }
#pragma unroll
      for (int j = 0; j < 4; ++j) { e0[j] = e1[j]; e1[j] = e2[j]; g0[j] = g1[j]; }
    }
  }

  float2 bb = ((const float2*)bias)[lane];
#pragma unroll
  for (int t = 0; t < 4; ++t) {
    int i = i0 + t;
    if (i < N) {
      float o0 = fmaxf(ax[t] + bb.x, 0.f);
      float o1 = fmaxf(ay[t] + bb.y, 0.f);
      if (OUTBF16) {
        unsigned pk = ((unsigned)f2bf(o1) << 16) | (unsigned)f2bf(o0);
        ((unsigned*)out)[(size_t)i * 64 + lane] = pk;
      } else {
        ((float2*)out)[(size_t)i * 64 + lane] = make_float2(o0, o1);
      }
    }
  }
}

// ---------------- launch ----------------

extern "C" void kernel_launch(void* const* d_in, const int* in_sizes, int n_in,
                              void* d_out, int out_size, void* d_ws, size_t ws_size,
                              hipStream_t stream) {
  const float* x = (const float*)d_in[0];
  const int* ei = (const int*)d_in[1];
  const float* Wg = (const float*)d_in[2];
  const float* b = (const float*)d_in[3];
  int N = in_sizes[0] / FD;
  int E = in_sizes[1] / 2;
  const int* src = ei;      // edge_index[0]
  const int* dst = ei + E;  // edge_index[1]

  char* p = (char*)d_ws;
  auto alloc = [&](size_t bytes) {
    void* r = (void*)p;
    p += (bytes + 255) & ~(size_t)255;
    return r;
  };
  int* deg = (int*)alloc((size_t)N * 4);
  int* cursor = (int*)alloc((size_t)N * 4);
  float* dis = (float*)alloc((size_t)N * 4);
  int* offtmp = (int*)alloc((size_t)N * 4);
  int nb = (N + 255) / 256;
  int* bsum = (int*)alloc((size_t)nb * 4);
  int* off = (int*)alloc((size_t)(N + 1) * 4);
  int2* ew = (int2*)alloc((size_t)E * 8);
  unsigned short* h = (unsigned short*)alloc((size_t)N * FD * 2);   // bf16 H
  unsigned short* xb = (unsigned short*)alloc((size_t)N * FD * 2);  // bf16 x (layers 1,2)
  short* wf_hi = (short*)alloc((size_t)FD * FD * 2);
  short* wf_lo = (short*)alloc((size_t)FD * FD * 2);

  hipMemsetAsync(deg, 0, (size_t)N * 4, stream);
  hipMemsetAsync(cursor, 0, (size_t)N * 4, stream);

  int gE = (E + 255) / 256, gN = (N + 255) / 256;
  k_count<<<gE, 256, 0, stream>>>(dst, deg, E);
  k_scanA<<<nb, 256, 0, stream>>>(deg, offtmp, bsum, dis, N);
  k_scanB<<<1, 512, 0, stream>>>(bsum, nb);
  k_scanC<<<gN, 256, 0, stream>>>(offtmp, bsum, off, N, E);
  k_fill<<<gE, 256, 0, stream>>>(src, dst, dis, off, cursor, ew, E);
  k_wsplit<<<FD * FD / 256, 256, 0, stream>>>(Wg, wf_hi, wf_lo);

  int gG = (N + 127) / 128;
  int gA = (N + 15) / 16;
  // layer 0: fp32 x -> h (full precision W); agg -> bf16 xb
  k_gemm<false, true><<<gG, 256, 0, stream>>>(x, wf_hi, wf_lo, h, N);
  k_agg<true><<<gA, 256, 0, stream>>>((const unsigned*)h, off, ew, dis, b, xb, N);
  // layer 1: bf16 xb -> h (W hi only); agg -> bf16 xb
  k_gemm<true, false><<<gG, 256, 0, stream>>>(xb, wf_hi, wf_lo, h, N);
  k_agg<true><<<gA, 256, 0, stream>>>((const unsigned*)h, off, ew, dis, b, xb, N);
  // layer 2: bf16 xb -> h (W hi only); agg -> fp32 d_out
  k_gemm<true, false><<<gG, 256, 0, stream>>>(xb, wf_hi, wf_lo, h, N);
  k_agg<false><<<gA, 256, 0, stream>>>((const unsigned*)h, off, ew, dis, b, d_out, N);
}